// Round 6
// baseline (25.935 us; speedup 1.0000x reference)
//
#include <hip/hip_runtime.h>

// Problem constants (match reference setup_inputs)
constexpr int B  = 16;
constexpr int T  = 32;
constexpr int NB = 8;
constexpr int L  = 128;
constexpr int V  = 50000;
constexpr int P  = NB * L;            // 1024 contributions per (b,t) row

constexpr int NCHUNK = 10;            // vocab chunks per row
constexpr int CHUNK  = V / NCHUNK;    // 5000 floats = 20000 B LDS
constexpr int CHUNK4 = CHUNK / 4;     // 1250 float4; chunk byte offset
                                      // (20000*chunk) is 16B-aligned

// Native vector type: __builtin_nontemporal_store rejects HIP_vector_type
// (float4 is a class), but accepts clang ext_vector_type.
typedef float f32x4 __attribute__((ext_vector_type(4)));

// One block per (row, vocab-chunk). Accumulate in LDS, then stream the
// chunk to global with NONTEMPORAL 16B stores (nt flag): the 102.4 MB
// output is never re-read, so bypassing L2 write-allocate avoids thrashing
// the 4 MB/XCD L2 that also holds the 10x-rescanned inputs.
// 20000 B LDS -> 8 blocks/CU = 32 waves/CU.
__global__ __launch_bounds__(256) void fused_lds_scatter_kernel(
    const float* __restrict__ bw,   // (B,T,NB)
    const float* __restrict__ att,  // (B,T,NB,L) == (B,T,P)
    const int*   __restrict__ idx,  // (B,NB,L)   == (B,P)
    float*       __restrict__ out)  // (B,T,V)
{
    __shared__ float buf[CHUNK];

    const int blk   = blockIdx.x;        // bt*NCHUNK + chunk
    const int bt    = blk / NCHUNK;      // consecutive blocks share a row,
    const int chunk = blk - bt * NCHUNK; // write contiguous vocab chunks
    const int b     = bt >> 5;           // / T (T==32)
    const int tid   = threadIdx.x;       // 0..255
    const int lo    = chunk * CHUNK;

    // Zero LDS chunk (ds_write_b128, conflict-free sequential pattern).
    f32x4* buf4 = reinterpret_cast<f32x4*>(buf);
    const f32x4 z = {0.f, 0.f, 0.f, 0.f};
    for (int i = tid; i < CHUNK4; i += 256)
        buf4[i] = z;

    // Load this row's 1024 contributions (coalesced; overlaps LDS zeroing).
    const float* attRow = att + bt * P;
    const float* bwRow  = bw  + bt * NB;
    const int*   idxRow = idx + b  * P;
    float val[4];
    int   v[4];
#pragma unroll
    for (int k = 0; k < 4; ++k) {
        const int p = tid + k * 256;
        val[k] = attRow[p] * bwRow[p >> 7];   // p>>7 == p/L == nb
        v[k]   = idxRow[p] - lo;              // position within this chunk
    }

    __syncthreads();  // LDS zeros visible (lgkm drain only — cheap)

    // Scatter the in-range subset (~1/10) into LDS.
#pragma unroll
    for (int k = 0; k < 4; ++k)
        if ((unsigned)v[k] < (unsigned)CHUNK)
            atomicAdd(&buf[v[k]], val[k]);

    __syncthreads();

    // Stream chunk to global: nontemporal 16B writes, last op in kernel.
    f32x4* dst = reinterpret_cast<f32x4*>(out + (size_t)bt * V + lo);
    for (int i = tid; i < CHUNK4; i += 256)
        __builtin_nontemporal_store(buf4[i], &dst[i]);
}

extern "C" void kernel_launch(void* const* d_in, const int* in_sizes, int n_in,
                              void* d_out, int out_size, void* d_ws, size_t ws_size,
                              hipStream_t stream) {
    const float* bw  = (const float*)d_in[0];
    const float* att = (const float*)d_in[1];
    const int*   idx = (const int*)d_in[2];
    float* out = (float*)d_out;

    fused_lds_scatter_kernel<<<B * T * NCHUNK, 256, 0, stream>>>(bw, att, idx, out);
}

// Round 7
// 20.955 us; speedup vs baseline: 1.2376x; 1.2376x over previous
//
#include <hip/hip_runtime.h>

// Problem constants (match reference setup_inputs)
constexpr int B  = 16;
constexpr int T  = 32;
constexpr int NB = 8;
constexpr int L  = 128;
constexpr int V  = 50000;
constexpr int P  = NB * L;            // 1024 contributions per (b,t) row

constexpr int NCHUNK = 10;            // vocab chunks per row
constexpr int CHUNK  = V / NCHUNK;    // 5000 floats = 20000 B LDS
constexpr int CHUNK4 = CHUNK / 4;     // 1250 float4 per chunk
constexpr int NASG   = B * T * NCHUNK;     // 5120 chunk-assignments
constexpr int ASG_PER_BLK = 4;             // each block does 4 consecutive
constexpr int NBLK   = NASG / ASG_PER_BLK; // 1280 = exactly 5 blocks/CU

typedef float f32x4 __attribute__((ext_vector_type(4)));

// One uniform residency round: 1280 blocks (5/CU, all resident at t=0),
// each looping over 4 consecutive chunk-assignments with a single 20 KB
// LDS accumulator. Per assignment: zero LDS || load the row's 1024
// contributions -> barrier -> LDS scatter (ds atomics resolve the ~1/10
// in-chunk duplicates) -> barrier -> stream 20 KB to global as plain
// float4 stores (NOT nontemporal: round-5 showed nt bypassing L2's
// write-coalescing costs +22%). The barrier's vmcnt drain only waits L2
// write *acceptance* of 5 outstanding dwordx4 stores (~hundreds of cycles),
// hidden by the other 19 resident waves/CU. Each block writes 80 KB
// contiguous; no tail round, prologue amortized 4x.
__global__ __launch_bounds__(256) void fused_lds_scatter_kernel(
    const float* __restrict__ bw,   // (B,T,NB)
    const float* __restrict__ att,  // (B,T,NB,L) == (B,T,P)
    const int*   __restrict__ idx,  // (B,NB,L)   == (B,P)
    float*       __restrict__ out)  // (B,T,V)
{
    __shared__ float buf[CHUNK];
    f32x4* buf4 = reinterpret_cast<f32x4*>(buf);
    const int tid = threadIdx.x;    // 0..255

    for (int j = 0; j < ASG_PER_BLK; ++j) {
        const int asg   = blockIdx.x * ASG_PER_BLK + j;  // contiguous output
        const int bt    = asg / NCHUNK;
        const int chunk = asg - bt * NCHUNK;
        const int b     = bt >> 5;           // / T (T==32)
        const int lo    = chunk * CHUNK;

        // Zero LDS chunk (ds_write_b128, conflict-free).
        const f32x4 z = {0.f, 0.f, 0.f, 0.f};
        for (int i = tid; i < CHUNK4; i += 256)
            buf4[i] = z;

        // Load this row's 1024 contributions (coalesced; L2-hot after
        // the first pass). Overlaps the LDS zeroing.
        const float* attRow = att + bt * P;
        const float* bwRow  = bw  + bt * NB;
        const int*   idxRow = idx + b  * P;
        float val[4];
        int   v[4];
#pragma unroll
        for (int k = 0; k < 4; ++k) {
            const int p = tid + k * 256;
            val[k] = attRow[p] * bwRow[p >> 7];   // p>>7 == p/L == nb
            v[k]   = idxRow[p] - lo;              // position within chunk
        }

        __syncthreads();  // zeros visible

        // Scatter the in-range subset (~1/10) into LDS.
#pragma unroll
        for (int k = 0; k < 4; ++k)
            if ((unsigned)v[k] < (unsigned)CHUNK)
                atomicAdd(&buf[v[k]], val[k]);

        __syncthreads();  // scatter complete

        // Stream chunk to global: plain float4 writes.
        f32x4* dst = reinterpret_cast<f32x4*>(out + (size_t)bt * V + lo);
        for (int i = tid; i < CHUNK4; i += 256)
            dst[i] = buf4[i];

        if (j + 1 < ASG_PER_BLK)
            __syncthreads();  // buf WAR: ds_reads done before re-zero
    }
}

extern "C" void kernel_launch(void* const* d_in, const int* in_sizes, int n_in,
                              void* d_out, int out_size, void* d_ws, size_t ws_size,
                              hipStream_t stream) {
    const float* bw  = (const float*)d_in[0];
    const float* att = (const float*)d_in[1];
    const int*   idx = (const int*)d_in[2];
    float* out = (float*)d_out;

    fused_lds_scatter_kernel<<<NBLK, 256, 0, stream>>>(bw, att, idx, out);
}